// Round 2
// baseline (1503.289 us; speedup 1.0000x reference)
//
#include <hip/hip_runtime.h>
#include <hip/hip_bf16.h>

typedef unsigned short u16;
typedef __attribute__((ext_vector_type(8))) short bf16x8;
typedef __attribute__((ext_vector_type(4))) float f32x4;

#define MFMA16(a,b,c) __builtin_amdgcn_mfma_f32_16x16x32_bf16(a,b,c,0,0,0)

__device__ __forceinline__ u16 f2bf(float f) {
  union { float f; unsigned u; } v; v.f = f;
  return (u16)((v.u + 0x7fffu + ((v.u >> 16) & 1u)) >> 16);
}
__device__ __forceinline__ float bf2f(u16 h) {
  union { unsigned u; float f; } v; v.u = ((unsigned)h) << 16;
  return v.f;
}
// group g in 0..11 (8 qk-head groups of 24q+24k, then 4 v-groups of 48), c in 0..47
__device__ __forceinline__ int qkv_ch(int g, int c) {
  if (g < 8) return (c < 24) ? (g*24 + c) : (192 + g*24 + (c - 24));
  return 384 + (g - 8)*48 + c;
}

// ---------------- K1: qkv 1x1 conv (bf16 MFMA GEMM, M=48 per block = one group) ----
// writes qkv1[b][g][s][48] bf16
__global__ __launch_bounds__(256) void k1_qkv(
    const float* __restrict__ x, const float* __restrict__ qkv_w,
    const float* __restrict__ qkv_b, u16* __restrict__ qkv1) {
  int p = blockIdx.x;                 // 24576 blocks, XCD-swizzled
  int xcd = p & 7, w = p >> 3;
  int g = w % 12;
  int pr = xcd * 256 + w / 12;        // 0..2047
  int bb = pr >> 9, nb = pr & 511;
  int s0 = nb << 7;                   // 128-pixel strip
  int t = threadIdx.x;
  int lane = t & 63, wid = t >> 6;
  int lg = lane >> 4, lr = lane & 15;

  __shared__ __align__(16) u16 Bt[128*192];   // x tile, [px][k] bf16, XOR-swizzled rows (384B)
  __shared__ __align__(16) u16 st[128*52];    // C staging, [px][48ch] pad->52

  // load B tile: x[bb][k][s0..s0+128) -> Bt (transpose), lanes interleave k to avoid bank conflicts
  const float* xb = x + (size_t)bb * (192*65536);
  for (int i = 0; i < 24; ++i) {
    int px4 = t >> 3;                 // 0..31
    int k = (t & 7) + 8*i;            // 0..191
    float4 v = *(const float4*)(xb + (size_t)k*65536 + s0 + px4*4);
    float vf[4] = {v.x, v.y, v.z, v.w};
    #pragma unroll
    for (int e = 0; e < 4; ++e) {
      int px = px4*4 + e;
      int byte = (px*384 + k*2) ^ ((px & 7) << 4);
      *(u16*)((char*)Bt + byte) = f2bf(vf[e]);
    }
  }

  // A frags straight from global (W is tiny, L2-hot): rows are permuted channels of this group
  bf16x8 a[3][6];
  #pragma unroll
  for (int mt = 0; mt < 3; ++mt) {
    int m = mt*16 + lr;
    int ch = qkv_ch(g, m);
    const float* wr = qkv_w + ch*192 + lg*8;
    #pragma unroll
    for (int ks = 0; ks < 6; ++ks) {
      float4 w0 = *(const float4*)(wr + ks*32);
      float4 w1 = *(const float4*)(wr + ks*32 + 4);
      bf16x8 af;
      af[0] = (short)f2bf(w0.x); af[1] = (short)f2bf(w0.y);
      af[2] = (short)f2bf(w0.z); af[3] = (short)f2bf(w0.w);
      af[4] = (short)f2bf(w1.x); af[5] = (short)f2bf(w1.y);
      af[6] = (short)f2bf(w1.z); af[7] = (short)f2bf(w1.w);
      a[mt][ks] = af;
    }
  }
  __syncthreads();

  f32x4 acc[3][2];
  #pragma unroll
  for (int mt = 0; mt < 3; ++mt)
    #pragma unroll
    for (int nt = 0; nt < 2; ++nt)
      acc[mt][nt] = (f32x4){0.f, 0.f, 0.f, 0.f};

  int n0 = wid*32;
  #pragma unroll
  for (int ks = 0; ks < 6; ++ks) {
    bf16x8 b[2];
    #pragma unroll
    for (int nt = 0; nt < 2; ++nt) {
      int px = n0 + nt*16 + lr;
      int byte = (px*384 + ks*64 + lg*16) ^ ((px & 7) << 4);
      b[nt] = *(const bf16x8*)((const char*)Bt + byte);
    }
    #pragma unroll
    for (int mt = 0; mt < 3; ++mt)
      #pragma unroll
      for (int nt = 0; nt < 2; ++nt)
        acc[mt][nt] = MFMA16(a[mt][ks], b[nt], acc[mt][nt]);
  }

  float bias[3][4];
  #pragma unroll
  for (int mt = 0; mt < 3; ++mt)
    #pragma unroll
    for (int r = 0; r < 4; ++r)
      bias[mt][r] = qkv_b[qkv_ch(g, mt*16 + lg*4 + r)];

  #pragma unroll
  for (int mt = 0; mt < 3; ++mt)
    #pragma unroll
    for (int nt = 0; nt < 2; ++nt) {
      int px = n0 + nt*16 + lr;
      int m0 = mt*16 + lg*4;
      ushort4 o;
      o.x = f2bf(acc[mt][nt][0] + bias[mt][0]);
      o.y = f2bf(acc[mt][nt][1] + bias[mt][1]);
      o.z = f2bf(acc[mt][nt][2] + bias[mt][2]);
      o.w = f2bf(acc[mt][nt][3] + bias[mt][3]);
      *(ushort4*)((char*)st + px*104 + m0*2) = o;
    }
  __syncthreads();

  u16* dst = qkv1 + ((size_t)(bb*12 + g) * 65536 + s0) * 48;
  #pragma unroll
  for (int i = 0; i < 6; ++i) {
    int j = t + (i << 8);             // < 1536; byte dest = j*8 (fully contiguous)
    int px = j / 12, c8 = j % 12;
    uint2 v = *(const uint2*)((const char*)st + px*104 + c8*8);
    *(uint2*)((char*)dst + (size_t)j*8) = v;
  }
}

// ---------------- K2: depthwise 3x3 + Gram partials (q,k) + v store -----------------
__global__ __launch_bounds__(256) void k2_dw(
    const u16* __restrict__ qkv1, const float* __restrict__ dw_w,
    const float* __restrict__ dw_b, u16* __restrict__ vd,
    float* __restrict__ partials) {
  int tx = blockIdx.x, ty = blockIdx.y, bb = blockIdx.z;
  int x0 = tx << 4, y0 = ty << 4;
  int t = threadIdx.x;

  __shared__ __align__(16) u16 in_t[324*48];   // 18x18 halo tile, [hp][c]
  __shared__ __align__(16) u16 out_t[256*48];  // dw output, [p][c]
  __shared__ float w9[48*9];
  __shared__ float wb[48];
  float* stage = (float*)in_t;                 // reuse after dw (4992 floats used)

  for (int g = 0; g < 12; ++g) {
    __syncthreads();  // protect in_t(stage)/out_t/w9 reuse from previous iteration
    for (int j = t; j < 480; j += 256) {
      if (j < 432) { int c = j / 9; w9[j] = dw_w[qkv_ch(g, c)*9 + (j % 9)]; }
      else         { int c = j - 432; wb[c] = dw_b[qkv_ch(g, c)]; }
    }
    const u16* src = qkv1 + (size_t)(bb*12 + g) * (65536*48);
    for (int j = t; j < 1944; j += 256) {      // 324 px * 6 chunks of 16B
      int hp = j / 6, c16 = j % 6;
      int hy = y0 - 1 + hp / 18, hx = x0 - 1 + hp % 18;
      uint4 v = {0u, 0u, 0u, 0u};
      if (hy >= 0 && hy < 256 && hx >= 0 && hx < 256)
        v = *(const uint4*)(src + ((size_t)hy*256 + hx)*48 + c16*8);
      *(uint4*)(in_t + hp*48 + c16*8) = v;
    }
    __syncthreads();

    for (int i = 0; i < 48; ++i) {             // dw conv: 256px * 48ch
      int j = t + (i << 8);
      int pp = j / 48, c = j % 48;
      int py = pp >> 4, px = pp & 15;
      float acc = wb[c];
      #pragma unroll
      for (int dy = 0; dy < 3; ++dy)
        #pragma unroll
        for (int dx = 0; dx < 3; ++dx)
          acc += bf2f(in_t[((py + dy)*18 + px + dx)*48 + c]) * w9[c*9 + dy*3 + dx];
      out_t[pp*48 + c] = f2bf(acc);
    }
    __syncthreads();

    if (g < 8) {
      // Gram: 36 pairs (4x4 c,d tiles) x 8 pixel-chunks + 12 diag groups x 8 chunks
      for (int jj = t; jj < 384; jj += 256) {
        if (jj < 288) {
          int pair = jj % 36, chunk = jj / 36;
          int c0 = (pair / 6)*4, d0 = 24 + (pair % 6)*4;
          float a16[16];
          #pragma unroll
          for (int e = 0; e < 16; ++e) a16[e] = 0.f;
          int p0 = chunk*32;
          for (int p = p0; p < p0 + 32; ++p) {
            ushort4 qv = *(const ushort4*)(out_t + p*48 + c0);
            ushort4 kv = *(const ushort4*)(out_t + p*48 + d0);
            float qf[4] = {bf2f(qv.x), bf2f(qv.y), bf2f(qv.z), bf2f(qv.w)};
            float kf[4] = {bf2f(kv.x), bf2f(kv.y), bf2f(kv.z), bf2f(kv.w)};
            #pragma unroll
            for (int ii = 0; ii < 4; ++ii)
              #pragma unroll
              for (int dj = 0; dj < 4; ++dj)
                a16[ii*4 + dj] += qf[ii] * kf[dj];
          }
          #pragma unroll
          for (int e = 0; e < 16; ++e) stage[(pair*8 + chunk)*16 + e] = a16[e];
        } else {
          int dj2 = jj - 288;
          int grp = dj2 % 12, chunk = dj2 / 12;
          int c0 = grp*4;
          float a4[4] = {0.f, 0.f, 0.f, 0.f};
          int p0 = chunk*32;
          for (int p = p0; p < p0 + 32; ++p) {
            ushort4 qv = *(const ushort4*)(out_t + p*48 + c0);
            float q0 = bf2f(qv.x), q1 = bf2f(qv.y), q2 = bf2f(qv.z), q3 = bf2f(qv.w);
            a4[0] += q0*q0; a4[1] += q1*q1; a4[2] += q2*q2; a4[3] += q3*q3;
          }
          #pragma unroll
          for (int e = 0; e < 4; ++e) stage[4608 + (grp*8 + chunk)*4 + e] = a4[e];
        }
      }
      __syncthreads();
      float* pdst = partials + (((size_t)bb*256 + (ty*16 + tx))*8 + g) * 640;
      for (int e = t; e < 624; e += 256) {
        float s = 0.f;
        if (e < 576) {
          int c = e / 24, d = e % 24;
          int pair = (c >> 2)*6 + (d >> 2);
          int idx = (c & 3)*4 + (d & 3);
          #pragma unroll
          for (int ch = 0; ch < 8; ++ch) s += stage[(pair*8 + ch)*16 + idx];
        } else {
          int cc = e - 576;
          int grp = cc >> 2, ii = cc & 3;
          #pragma unroll
          for (int ch = 0; ch < 8; ++ch) s += stage[4608 + (grp*8 + ch)*4 + ii];
        }
        pdst[e] = s;
      }
    } else {
      // v groups: write vd[b][s][192] bf16
      u16* dst = vd + (size_t)bb * (65536*192);
      for (int i = 0; i < 6; ++i) {
        int j = t + (i << 8);                  // 256px * 6 chunks of 16B
        int pp = j / 6, c16 = j % 6;
        int py = pp >> 4, px = pp & 15;
        size_t s = (size_t)(y0 + py)*256 + (x0 + px);
        uint4 v = *(const uint4*)(out_t + pp*48 + c16*8);
        *(uint4*)(dst + s*192 + (g - 8)*48 + c16*8) = v;
      }
    }
  }
}

// ---------------- K3a: reduce Gram partials over 256 blocks ------------------------
__global__ __launch_bounds__(256) void k3a(
    const float* __restrict__ partials, float* __restrict__ G) {
  int bb = blockIdx.x, h = blockIdx.y;
  int t = threadIdx.x;
  for (int e = t; e < 624; e += 256) {
    const float* p = partials + ((size_t)bb*256*8 + h)*640 + e;
    float s = 0.f;
    for (int blk = 0; blk < 256; ++blk) s += p[(size_t)blk * (8*640)];
    G[(size_t)(bb*8 + h)*640 + e] = s;
  }
}

// ---------------- K3b: norms + softmax + fold proj into M_b[192][192] --------------
__global__ __launch_bounds__(256) void k3b(
    const float* __restrict__ G, const float* __restrict__ scale,
    const float* __restrict__ proj_w, u16* __restrict__ M) {
  int bb = blockIdx.x;
  int t = threadIdx.x;
  __shared__ float attn[8*24*24];
  if (t < 192) {
    int h = t / 24, c = t % 24;
    const float* Gh = G + (size_t)(bb*8 + h)*640;
    float qn = fmaxf(sqrtf(fmaxf(Gh[576 + c], 0.f)), 1e-12f);
    float sc = scale[h];
    float L[24];
    float mx = -1e30f;
    #pragma unroll
    for (int d = 0; d < 24; ++d) {
      float kn = fmaxf(sqrtf(fmaxf(Gh[600 + d], 0.f)), 1e-12f);
      L[d] = Gh[c*24 + d] / (qn * kn) * sc;
      mx = fmaxf(mx, L[d]);
    }
    float ssum = 0.f;
    #pragma unroll
    for (int d = 0; d < 24; ++d) { L[d] = __expf(L[d] - mx); ssum += L[d]; }
    float inv = 1.f / ssum;
    #pragma unroll
    for (int d = 0; d < 24; ++d) attn[(h*24 + c)*24 + d] = L[d] * inv;
  }
  __syncthreads();
  // M[co][h*24+d] = sum_c P[co][h*24+c] * attn[h][c][d]
  for (int j = t; j < 36864; j += 256) {
    int co = j / 192, cd = j % 192;
    int h = cd / 24, d = cd % 24;
    const float* Pr = proj_w + co*192 + h*24;
    const float* Ar = attn + h*576 + d;
    float s = 0.f;
    #pragma unroll
    for (int c = 0; c < 24; ++c) s += Pr[c] * Ar[c*24];
    M[(size_t)bb*36864 + j] = f2bf(s);
  }
}

// ---------------- K4: y = M_b @ v + proj_b (bf16 MFMA GEMM, fp32 out) --------------
__global__ __launch_bounds__(256) void k4_out(
    const u16* __restrict__ vd, const u16* __restrict__ M,
    const float* __restrict__ proj_b, float* __restrict__ out) {
  int p = blockIdx.x;                 // 8192, XCD-swizzled so both mb of one nb co-locate
  int xcd = p & 7, w = p >> 3;
  int mb = w & 1;
  int pr = xcd*512 + (w >> 1);        // 0..4095
  int bb = pr >> 10, nb = pr & 1023;
  int s0 = nb << 6;                   // 64 pixels
  int t = threadIdx.x;
  int lane = t & 63, wid = t >> 6;
  int lg = lane >> 4, lr = lane & 15;

  __shared__ __align__(16) u16 A[96*192];   // M rows, swizzled
  __shared__ __align__(16) u16 B[64*192];   // v pixels, swizzled

  const u16* Ms = M + ((size_t)bb*192 + mb*96) * 192;
  for (int j = t; j < 2304; j += 256) {     // 96 rows * 24 chunks of 16B (FULL 384B rows)
    int m = j / 24, c16 = j % 24;
    uint4 v = *(const uint4*)(Ms + m*192 + c16*8);
    int byte = (m*384 + c16*16) ^ ((m & 7) << 4);
    *(uint4*)((char*)A + byte) = v;
  }
  const u16* Bs = vd + ((size_t)bb*65536 + s0) * 192;
  for (int j = t; j < 1536; j += 256) {     // 64 px * 24 chunks of 16B (FULL 384B rows)
    int px = j / 24, c16 = j % 24;
    uint4 v = *(const uint4*)(Bs + px*192 + c16*8);
    int byte = (px*384 + c16*16) ^ ((px & 7) << 4);
    *(uint4*)((char*)B + byte) = v;
  }
  __syncthreads();

  int wr = wid >> 1, wc = wid & 1;          // wave tile 48x32
  f32x4 acc[3][2];
  #pragma unroll
  for (int mt = 0; mt < 3; ++mt)
    #pragma unroll
    for (int nt = 0; nt < 2; ++nt)
      acc[mt][nt] = (f32x4){0.f, 0.f, 0.f, 0.f};

  #pragma unroll
  for (int ks = 0; ks < 6; ++ks) {
    bf16x8 af[3], bf[2];
    #pragma unroll
    for (int mt = 0; mt < 3; ++mt) {
      int m = wr*48 + mt*16 + lr;
      int byte = (m*384 + ks*64 + lg*16) ^ ((m & 7) << 4);
      af[mt] = *(const bf16x8*)((const char*)A + byte);
    }
    #pragma unroll
    for (int nt = 0; nt < 2; ++nt) {
      int px = wc*32 + nt*16 + lr;
      int byte = (px*384 + ks*64 + lg*16) ^ ((px & 7) << 4);
      bf[nt] = *(const bf16x8*)((const char*)B + byte);
    }
    #pragma unroll
    for (int mt = 0; mt < 3; ++mt)
      #pragma unroll
      for (int nt = 0; nt < 2; ++nt)
        acc[mt][nt] = MFMA16(af[mt], bf[nt], acc[mt][nt]);
  }
  __syncthreads();
  float* stg = (float*)A;                   // [96][68] f32 = 26112B <= 36864B
  #pragma unroll
  for (int mt = 0; mt < 3; ++mt)
    #pragma unroll
    for (int nt = 0; nt < 2; ++nt) {
      int m0 = wr*48 + mt*16 + lg*4;
      int px = wc*32 + nt*16 + lr;
      #pragma unroll
      for (int r = 0; r < 4; ++r)
        stg[(m0 + r)*68 + px] = acc[mt][nt][r];
    }
  __syncthreads();
  float* dst = out + ((size_t)bb*192 + mb*96) * 65536 + s0;
  const float* pb = proj_b + mb*96;
  #pragma unroll
  for (int i = 0; i < 6; ++i) {
    int j = t + (i << 8);                   // < 1536: 96 rows * 16 chunks of 16B
    int m = j >> 4, c4 = j & 15;
    float4 v = *(const float4*)(stg + m*68 + c4*4);
    float b = pb[m];
    v.x += b; v.y += b; v.z += b; v.w += b;
    *(float4*)(dst + (size_t)m*65536 + c4*4) = v;
  }
}

extern "C" void kernel_launch(void* const* d_in, const int* in_sizes, int n_in,
                              void* d_out, int out_size, void* d_ws, size_t ws_size,
                              hipStream_t stream) {
  (void)in_sizes; (void)n_in; (void)out_size; (void)ws_size;
  const float* x      = (const float*)d_in[0];
  const float* qkv_w  = (const float*)d_in[1];
  const float* qkv_b  = (const float*)d_in[2];
  const float* dw_w   = (const float*)d_in[3];
  const float* dw_b   = (const float*)d_in[4];
  const float* scale  = (const float*)d_in[5];
  const float* proj_w = (const float*)d_in[6];
  const float* proj_b = (const float*)d_in[7];
  float* out = (float*)d_out;
  char* ws = (char*)d_ws;

  // workspace layout (bytes): qkv1 302MB | vd 101MB | partials 21MB | G | M  (~424MB)
  u16*   qkv1     = (u16*)(ws);
  u16*   vd       = (u16*)(ws + 301989888ULL);
  float* partials = (float*)(ws + 402653184ULL);
  float* G        = (float*)(ws + 423624704ULL);
  u16*   M        = (u16*)(ws + 423706624ULL);

  k1_qkv<<<dim3(24576), dim3(256), 0, stream>>>(x, qkv_w, qkv_b, qkv1);
  k2_dw<<<dim3(16, 16, 4), dim3(256), 0, stream>>>(qkv1, dw_w, dw_b, vd, partials);
  k3a<<<dim3(4, 8), dim3(256), 0, stream>>>(partials, G);
  k3b<<<dim3(4), dim3(256), 0, stream>>>(G, scale, proj_w, M);
  k4_out<<<dim3(8192), dim3(256), 0, stream>>>(vd, M, proj_b, out);
}

// Round 3
// 802.288 us; speedup vs baseline: 1.8738x; 1.8738x over previous
//
#include <hip/hip_runtime.h>
#include <hip/hip_bf16.h>

typedef unsigned short u16;
typedef __attribute__((ext_vector_type(8))) short bf16x8;
typedef __attribute__((ext_vector_type(4))) float f32x4;

#define MFMA16(a,b,c) __builtin_amdgcn_mfma_f32_16x16x32_bf16(a,b,c,0,0,0)

__device__ __forceinline__ u16 f2bf(float f) {
  union { float f; unsigned u; } v; v.f = f;
  return (u16)((v.u + 0x7fffu + ((v.u >> 16) & 1u)) >> 16);
}
__device__ __forceinline__ float bf2f(u16 h) {
  union { unsigned u; float f; } v; v.u = ((unsigned)h) << 16;
  return v.f;
}
// group g in 0..11 (8 qk-head groups of 24q+24k, then 4 v-groups of 48), c in 0..47
__device__ __forceinline__ int qkv_ch(int g, int c) {
  if (g < 8) return (c < 24) ? (g*24 + c) : (192 + g*24 + (c - 24));
  return 384 + (g - 8)*48 + c;
}

// ---------------- K0: pre-permute + bf16-convert qkv weights ------------------------
// Wb[m][k] (m = g*48+c permuted order), Bp[m] f32 bias
__global__ __launch_bounds__(256) void k0_wb(
    const float* __restrict__ qkv_w, const float* __restrict__ qkv_b,
    u16* __restrict__ Wb, float* __restrict__ Bp) {
  int j = blockIdx.x*256 + threadIdx.x;          // 432 blocks -> 110592 = 576*192
  int m = j / 192, k = j % 192;
  Wb[j] = f2bf(qkv_w[qkv_ch(m/48, m%48)*192 + k]);
  if (j < 576) Bp[j] = qkv_b[qkv_ch(j/48, j%48)];
}

// ---------------- K1: qkv 1x1 conv, M=576 per block (bf16 MFMA GEMM) ----------------
// writes qkv1[b][g][s][48] bf16
__global__ __launch_bounds__(512) void k1_qkv(
    const float* __restrict__ x, const u16* __restrict__ Wb,
    const float* __restrict__ Bp, u16* __restrict__ qkv1) {
  int blk = blockIdx.x;               // 2048 = 4 bb * 512 strips
  int bb = blk >> 9, nb = blk & 511;
  int s0 = nb << 7;                   // 128-pixel strip
  int t = threadIdx.x;
  int lane = t & 63, wid = t >> 6;    // 8 waves
  int lg = lane >> 4, lr = lane & 15;
  int wr = wid >> 1, wc = wid & 1;    // wr: group-in-pass, wc: px half

  __shared__ __align__(16) u16 Bt[128*192];   // x^T tile [px][k], XOR-swizzled

  // stage x strip: thread -> (k-oct, px4); 16B LDS writes
  const float* xb = x + (size_t)bb*(192*65536) + s0;
  {
    int px4 = t & 31, kO = t >> 5;    // kO 0..15, then +16 (partial round)
    #pragma unroll
    for (int rnd = 0; rnd < 2; ++rnd, kO += 16) {
      if (kO < 24) {
        float4 f[8];
        #pragma unroll
        for (int j = 0; j < 8; ++j)
          f[j] = *(const float4*)(xb + (size_t)(kO*8 + j)*65536 + px4*4);
        #pragma unroll
        for (int e = 0; e < 4; ++e) {
          int px = px4*4 + e;
          bf16x8 h;
          #pragma unroll
          for (int j = 0; j < 8; ++j)
            h[j] = (short)f2bf(((const float*)&f[j])[e]);
          int byte = (px*384 + kO*16) ^ ((px & 7) << 4);
          *(bf16x8*)((char*)Bt + byte) = h;
        }
      }
    }
  }
  __syncthreads();

  #pragma unroll 1
  for (int pass = 0; pass < 3; ++pass) {
    int g = pass*4 + wr;
    // A fragments straight from global (L2-hot, 221KB total)
    bf16x8 af[3][6];
    #pragma unroll
    for (int mt = 0; mt < 3; ++mt) {
      const u16* wrp = Wb + (size_t)(g*48 + mt*16 + lr)*192 + lg*8;
      #pragma unroll
      for (int ks = 0; ks < 6; ++ks)
        af[mt][ks] = *(const bf16x8*)(wrp + ks*32);
    }
    f32x4 acc[3][4];
    #pragma unroll
    for (int mt = 0; mt < 3; ++mt)
      #pragma unroll
      for (int nt = 0; nt < 4; ++nt)
        acc[mt][nt] = (f32x4){0.f, 0.f, 0.f, 0.f};

    #pragma unroll
    for (int ks = 0; ks < 6; ++ks) {
      bf16x8 bf[4];
      #pragma unroll
      for (int nt = 0; nt < 4; ++nt) {
        int px = wc*64 + nt*16 + lr;
        int byte = (px*384 + ks*64 + lg*16) ^ ((px & 7) << 4);
        bf[nt] = *(const bf16x8*)((const char*)Bt + byte);
      }
      #pragma unroll
      for (int mt = 0; mt < 3; ++mt)
        #pragma unroll
        for (int nt = 0; nt < 4; ++nt)
          acc[mt][nt] = MFMA16(af[mt][ks], bf[nt], acc[mt][nt]);
    }

    // epilogue: bias + direct ushort4 stores (L2 write-combined)
    u16* dst = qkv1 + ((size_t)(bb*12 + g)*65536 + s0)*48;
    #pragma unroll
    for (int mt = 0; mt < 3; ++mt) {
      float4 bv = *(const float4*)(Bp + g*48 + mt*16 + lg*4);
      #pragma unroll
      for (int nt = 0; nt < 4; ++nt) {
        int px = wc*64 + nt*16 + lr;
        ushort4 o;
        o.x = f2bf(acc[mt][nt][0] + bv.x);
        o.y = f2bf(acc[mt][nt][1] + bv.y);
        o.z = f2bf(acc[mt][nt][2] + bv.z);
        o.w = f2bf(acc[mt][nt][3] + bv.w);
        *(ushort4*)(dst + (size_t)px*48 + mt*16 + lg*4) = o;
      }
    }
  }
}

// ---------------- K2: depthwise 3x3 + Gram partials (q,k) + v store -----------------
__global__ __launch_bounds__(256) void k2_dw(
    const u16* __restrict__ qkv1, const float* __restrict__ dw_w,
    const float* __restrict__ dw_b, u16* __restrict__ vd,
    float* __restrict__ partials) {
  int tx = blockIdx.x, ty = blockIdx.y, bb = blockIdx.z;
  int x0 = tx << 4, y0 = ty << 4;
  int t = threadIdx.x;

  __shared__ __align__(16) u16 in_t[48*440];   // c-major halo: [c][row*24+col], rows 18x18 used
  __shared__ __align__(16) u16 out_t[256*48];  // dw output, [p][c]
  __shared__ float w9[48*9];
  __shared__ float wb[48];
  float* stage = (float*)in_t;                 // reuse after dw (4992 floats used)

  for (int g = 0; g < 12; ++g) {
    __syncthreads();  // protect in_t(stage)/out_t/w9 reuse from previous iteration
    for (int j = t; j < 480; j += 256) {
      if (j < 432) { int c = j / 9; w9[j] = dw_w[qkv_ch(g, c)*9 + (j % 9)]; }
      else         { int c = j - 432; wb[c] = dw_b[qkv_ch(g, c)]; }
    }
    const u16* src = qkv1 + (size_t)(bb*12 + g) * (65536*48);
    for (int j = t; j < 1944; j += 256) {      // 324 halo px * 6 chunks of 16B
      int hp = j / 6, c16 = j % 6;
      int hr = hp / 18, hc = hp % 18;
      int hy = y0 - 1 + hr, hx = x0 - 1 + hc;
      uint4 v = {0u, 0u, 0u, 0u};
      if (hy >= 0 && hy < 256 && hx >= 0 && hx < 256)
        v = *(const uint4*)(src + ((size_t)hy*256 + hx)*48 + c16*8);
      const u16* us = (const u16*)&v;
      #pragma unroll
      for (int cc = 0; cc < 8; ++cc)
        in_t[(c16*8 + cc)*440 + hr*24 + hc] = us[cc];
    }
    __syncthreads();

    // dw conv: item = (c, 16-px row); wide LDS reads, taps shared in regs
    #pragma unroll 1
    for (int r2 = 0; r2 < 3; ++r2) {
      int item = t + (r2 << 8);                // 768 items
      int c = item % 48, row = item / 48;      // row 0..15
      float wv[9];
      #pragma unroll
      for (int i = 0; i < 9; ++i) wv[i] = w9[c*9 + i];
      float bias = wb[c];
      float rowf[3][18];
      #pragma unroll
      for (int dy = 0; dy < 3; ++dy) {
        int base = c*440 + (row + dy)*24;
        u16 hrow[18];
        *(uint4*)(hrow)     = *(const uint4*)(in_t + base);
        *(uint4*)(hrow + 8) = *(const uint4*)(in_t + base + 8);
        *(uint*)(hrow + 16) = *(const uint*)(in_t + base + 16);
        #pragma unroll
        for (int i2 = 0; i2 < 18; ++i2) rowf[dy][i2] = bf2f(hrow[i2]);
      }
      #pragma unroll
      for (int p = 0; p < 16; ++p) {
        float acc = bias;
        #pragma unroll
        for (int dy = 0; dy < 3; ++dy)
          acc += rowf[dy][p]*wv[dy*3] + rowf[dy][p+1]*wv[dy*3+1] + rowf[dy][p+2]*wv[dy*3+2];
        out_t[(row*16 + p)*48 + c] = f2bf(acc);
      }
    }
    __syncthreads();

    if (g < 8) {
      // Gram: 36 pairs (4x4 c,d tiles) x 8 pixel-chunks + 12 diag groups x 8 chunks
      for (int jj = t; jj < 384; jj += 256) {
        if (jj < 288) {
          int pair = jj % 36, chunk = jj / 36;
          int c0 = (pair / 6)*4, d0 = 24 + (pair % 6)*4;
          float a16[16];
          #pragma unroll
          for (int e = 0; e < 16; ++e) a16[e] = 0.f;
          int p0 = chunk*32;
          for (int p = p0; p < p0 + 32; ++p) {
            ushort4 qv = *(const ushort4*)(out_t + p*48 + c0);
            ushort4 kv = *(const ushort4*)(out_t + p*48 + d0);
            float qf[4] = {bf2f(qv.x), bf2f(qv.y), bf2f(qv.z), bf2f(qv.w)};
            float kf[4] = {bf2f(kv.x), bf2f(kv.y), bf2f(kv.z), bf2f(kv.w)};
            #pragma unroll
            for (int ii = 0; ii < 4; ++ii)
              #pragma unroll
              for (int dj = 0; dj < 4; ++dj)
                a16[ii*4 + dj] += qf[ii] * kf[dj];
          }
          #pragma unroll
          for (int e = 0; e < 16; ++e) stage[(pair*8 + chunk)*16 + e] = a16[e];
        } else {
          int dj2 = jj - 288;
          int grp = dj2 % 12, chunk = dj2 / 12;
          int c0 = grp*4;
          float a4[4] = {0.f, 0.f, 0.f, 0.f};
          int p0 = chunk*32;
          for (int p = p0; p < p0 + 32; ++p) {
            ushort4 qv = *(const ushort4*)(out_t + p*48 + c0);
            float q0 = bf2f(qv.x), q1 = bf2f(qv.y), q2 = bf2f(qv.z), q3 = bf2f(qv.w);
            a4[0] += q0*q0; a4[1] += q1*q1; a4[2] += q2*q2; a4[3] += q3*q3;
          }
          #pragma unroll
          for (int e = 0; e < 4; ++e) stage[4608 + (grp*8 + chunk)*4 + e] = a4[e];
        }
      }
      __syncthreads();
      float* pdst = partials + (((size_t)bb*256 + (ty*16 + tx))*8 + g) * 640;
      for (int e = t; e < 624; e += 256) {
        float s = 0.f;
        if (e < 576) {
          int c = e / 24, d = e % 24;
          int pair = (c >> 2)*6 + (d >> 2);
          int idx = (c & 3)*4 + (d & 3);
          #pragma unroll
          for (int ch = 0; ch < 8; ++ch) s += stage[(pair*8 + ch)*16 + idx];
        } else {
          int cc = e - 576;
          int grp = cc >> 2, ii = cc & 3;
          #pragma unroll
          for (int ch = 0; ch < 8; ++ch) s += stage[4608 + (grp*8 + ch)*4 + ii];
        }
        pdst[e] = s;
      }
    } else {
      // v groups: write vd[b][s][192] bf16
      u16* dst = vd + (size_t)bb * (65536*192);
      for (int i = 0; i < 6; ++i) {
        int j = t + (i << 8);                  // 256px * 6 chunks of 16B
        int pp = j / 6, c16 = j % 6;
        int py = pp >> 4, px = pp & 15;
        size_t s = (size_t)(y0 + py)*256 + (x0 + px);
        uint4 v = *(const uint4*)(out_t + pp*48 + c16*8);
        *(uint4*)(dst + s*192 + (g - 8)*48 + c16*8) = v;
      }
    }
  }
}

// ---------------- K3a: reduce Gram partials (8 chunks of 32 blocks) -----------------
__global__ __launch_bounds__(256) void k3a(
    const float* __restrict__ partials, float* __restrict__ G2) {
  int bb = blockIdx.x, h = blockIdx.y, ch = blockIdx.z;  // 4,8,8
  int t = threadIdx.x;
  for (int e = t; e < 624; e += 256) {
    const float* p = partials + ((size_t)(bb*256 + ch*32)*8 + h)*640 + e;
    float s = 0.f;
    #pragma unroll 4
    for (int blk = 0; blk < 32; ++blk) s += p[(size_t)blk * (8*640)];
    G2[(size_t)((bb*8 + h)*8 + ch)*640 + e] = s;
  }
}

// ---------------- K3b: norms + softmax + fold proj into M_b[192][192] --------------
__global__ __launch_bounds__(256) void k3b(
    const float* __restrict__ G2, const float* __restrict__ scale,
    const float* __restrict__ proj_w, u16* __restrict__ M) {
  int bb = blockIdx.x;
  int t = threadIdx.x;
  __shared__ float Gs[8*640];
  __shared__ float attn[8*24*24];
  for (int j = t; j < 5120; j += 256) {
    int h = j / 640, e = j % 640;
    float s = 0.f;
    #pragma unroll
    for (int ch = 0; ch < 8; ++ch)
      s += G2[(size_t)((bb*8 + h)*8 + ch)*640 + e];
    Gs[j] = s;
  }
  __syncthreads();
  if (t < 192) {
    int h = t / 24, c = t % 24;
    const float* Gh = Gs + h*640;
    float qn = fmaxf(sqrtf(fmaxf(Gh[576 + c], 0.f)), 1e-12f);
    float sc = scale[h];
    float L[24];
    float mx = -1e30f;
    #pragma unroll
    for (int d = 0; d < 24; ++d) {
      float kn = fmaxf(sqrtf(fmaxf(Gh[600 + d], 0.f)), 1e-12f);
      L[d] = Gh[c*24 + d] / (qn * kn) * sc;
      mx = fmaxf(mx, L[d]);
    }
    float ssum = 0.f;
    #pragma unroll
    for (int d = 0; d < 24; ++d) { L[d] = __expf(L[d] - mx); ssum += L[d]; }
    float inv = 1.f / ssum;
    #pragma unroll
    for (int d = 0; d < 24; ++d) attn[(h*24 + c)*24 + d] = L[d] * inv;
  }
  __syncthreads();
  // M[co][h*24+d] = sum_c P[co][h*24+c] * attn[h][c][d]
  for (int j = t; j < 36864; j += 256) {
    int co = j / 192, cd = j % 192;
    int h = cd / 24, d = cd % 24;
    const float* Pr = proj_w + co*192 + h*24;
    const float* Ar = attn + h*576 + d;
    float s = 0.f;
    #pragma unroll
    for (int c = 0; c < 24; ++c) s += Pr[c] * Ar[c*24];
    M[(size_t)bb*36864 + j] = f2bf(s);
  }
}

// ---------------- K4: y = M_b @ v + proj_b (bf16 MFMA GEMM, fp32 out) --------------
__global__ __launch_bounds__(256) void k4_out(
    const u16* __restrict__ vd, const u16* __restrict__ M,
    const float* __restrict__ proj_b, float* __restrict__ out) {
  int p = blockIdx.x;                 // 8192, XCD-swizzled so both mb of one nb co-locate
  int xcd = p & 7, w = p >> 3;
  int mb = w & 1;
  int pr = xcd*512 + (w >> 1);        // 0..4095
  int bb = pr >> 10, nb = pr & 1023;
  int s0 = nb << 6;                   // 64 pixels
  int t = threadIdx.x;
  int lane = t & 63, wid = t >> 6;
  int lg = lane >> 4, lr = lane & 15;

  __shared__ __align__(16) u16 A[96*192];   // M rows, swizzled
  __shared__ __align__(16) u16 B[64*192];   // v pixels, swizzled

  const u16* Ms = M + ((size_t)bb*192 + mb*96) * 192;
  for (int j = t; j < 2304; j += 256) {     // 96 rows * 24 chunks of 16B
    int m = j / 24, c16 = j % 24;
    uint4 v = *(const uint4*)(Ms + m*192 + c16*8);
    int byte = (m*384 + c16*16) ^ ((m & 7) << 4);
    *(uint4*)((char*)A + byte) = v;
  }
  const u16* Bs = vd + ((size_t)bb*65536 + s0) * 192;
  for (int j = t; j < 1536; j += 256) {     // 64 px * 24 chunks of 16B
    int px = j / 24, c16 = j % 24;
    uint4 v = *(const uint4*)(Bs + px*192 + c16*8);
    int byte = (px*384 + c16*16) ^ ((px & 7) << 4);
    *(uint4*)((char*)B + byte) = v;
  }
  __syncthreads();

  int wr = wid >> 1, wc = wid & 1;          // wave tile 48x32
  f32x4 acc[3][2];
  #pragma unroll
  for (int mt = 0; mt < 3; ++mt)
    #pragma unroll
    for (int nt = 0; nt < 2; ++nt)
      acc[mt][nt] = (f32x4){0.f, 0.f, 0.f, 0.f};

  #pragma unroll
  for (int ks = 0; ks < 6; ++ks) {
    bf16x8 af[3], bf[2];
    #pragma unroll
    for (int mt = 0; mt < 3; ++mt) {
      int m = wr*48 + mt*16 + lr;
      int byte = (m*384 + ks*64 + lg*16) ^ ((m & 7) << 4);
      af[mt] = *(const bf16x8*)((const char*)A + byte);
    }
    #pragma unroll
    for (int nt = 0; nt < 2; ++nt) {
      int px = wc*32 + nt*16 + lr;
      int byte = (px*384 + ks*64 + lg*16) ^ ((px & 7) << 4);
      bf[nt] = *(const bf16x8*)((const char*)B + byte);
    }
    #pragma unroll
    for (int mt = 0; mt < 3; ++mt)
      #pragma unroll
      for (int nt = 0; nt < 2; ++nt)
        acc[mt][nt] = MFMA16(af[mt], bf[nt], acc[mt][nt]);
  }
  __syncthreads();
  float* stg = (float*)A;                   // [96][68] f32 = 26112B <= 36864B
  #pragma unroll
  for (int mt = 0; mt < 3; ++mt)
    #pragma unroll
    for (int nt = 0; nt < 2; ++nt) {
      int m0 = wr*48 + mt*16 + lg*4;
      int px = wc*32 + nt*16 + lr;
      #pragma unroll
      for (int r = 0; r < 4; ++r)
        stg[(m0 + r)*68 + px] = acc[mt][nt][r];
    }
  __syncthreads();
  float* dst = out + ((size_t)bb*192 + mb*96) * 65536 + s0;
  const float* pb = proj_b + mb*96;
  #pragma unroll
  for (int i = 0; i < 6; ++i) {
    int j = t + (i << 8);                   // 96 rows * 16 chunks of 16B
    int m = j >> 4, c4 = j & 15;
    float4 v = *(const float4*)(stg + m*68 + c4*4);
    float b = pb[m];
    v.x += b; v.y += b; v.z += b; v.w += b;
    *(float4*)(dst + (size_t)m*65536 + c4*4) = v;
  }
}

extern "C" void kernel_launch(void* const* d_in, const int* in_sizes, int n_in,
                              void* d_out, int out_size, void* d_ws, size_t ws_size,
                              hipStream_t stream) {
  (void)in_sizes; (void)n_in; (void)out_size; (void)ws_size;
  const float* x      = (const float*)d_in[0];
  const float* qkv_w  = (const float*)d_in[1];
  const float* qkv_b  = (const float*)d_in[2];
  const float* dw_w   = (const float*)d_in[3];
  const float* dw_b   = (const float*)d_in[4];
  const float* scale  = (const float*)d_in[5];
  const float* proj_w = (const float*)d_in[6];
  const float* proj_b = (const float*)d_in[7];
  float* out = (float*)d_out;
  char* ws = (char*)d_ws;

  // workspace: qkv1 302MB | vd 101MB | partials 21MB. Time-multiplexed overlays:
  //   Wb/Bp live in the partials region (written by k0, read by k1, dead before k2)
  //   G2/M live in the qkv1 region (written by k3a/k3b, after k2's last qkv1 read)
  u16*   qkv1     = (u16*)(ws);
  u16*   vd       = (u16*)(ws + 301989888ULL);
  float* partials = (float*)(ws + 402653184ULL);
  u16*   Wb       = (u16*)(ws + 402653184ULL);
  float* Bp       = (float*)(ws + 402653184ULL + 221184ULL);
  float* G2       = (float*)(ws);
  u16*   M        = (u16*)(ws + 1048576ULL);

  k0_wb<<<dim3(432), dim3(256), 0, stream>>>(qkv_w, qkv_b, Wb, Bp);
  k1_qkv<<<dim3(2048), dim3(512), 0, stream>>>(x, Wb, Bp, qkv1);
  k2_dw<<<dim3(16, 16, 4), dim3(256), 0, stream>>>(qkv1, dw_w, dw_b, vd, partials);
  k3a<<<dim3(4, 8, 8), dim3(256), 0, stream>>>(partials, G2);
  k3b<<<dim3(4), dim3(256), 0, stream>>>(G2, scale, proj_w, M);
  k4_out<<<dim3(8192), dim3(256), 0, stream>>>(vd, M, proj_b, out);
}

// Round 4
// 765.428 us; speedup vs baseline: 1.9640x; 1.0482x over previous
//
#include <hip/hip_runtime.h>
#include <hip/hip_bf16.h>

typedef unsigned short u16;
typedef __attribute__((ext_vector_type(8))) short bf16x8;
typedef __attribute__((ext_vector_type(4))) float f32x4;

#define MFMA16(a,b,c) __builtin_amdgcn_mfma_f32_16x16x32_bf16(a,b,c,0,0,0)

__device__ __forceinline__ u16 f2bf(float f) {
  union { float f; unsigned u; } v; v.f = f;
  return (u16)((v.u + 0x7fffu + ((v.u >> 16) & 1u)) >> 16);
}
__device__ __forceinline__ float bf2f(u16 h) {
  union { unsigned u; float f; } v; v.u = ((unsigned)h) << 16;
  return v.f;
}
// group g in 0..11 (8 qk-head groups of 24q+24k, then 4 v-groups of 48), c in 0..47
__device__ __forceinline__ int qkv_ch(int g, int c) {
  if (g < 8) return (c < 24) ? (g*24 + c) : (192 + g*24 + (c - 24));
  return 384 + (g - 8)*48 + c;
}

// ---------------- K0: pre-permute + bf16-convert qkv weights ------------------------
__global__ __launch_bounds__(256) void k0_wb(
    const float* __restrict__ qkv_w, const float* __restrict__ qkv_b,
    u16* __restrict__ Wb, float* __restrict__ Bp) {
  int j = blockIdx.x*256 + threadIdx.x;          // 432 blocks -> 110592 = 576*192
  int m = j / 192, k = j % 192;
  Wb[j] = f2bf(qkv_w[qkv_ch(m/48, m%48)*192 + k]);
  if (j < 576) Bp[j] = qkv_b[qkv_ch(j/48, j%48)];
}

// ---------------- K1: qkv 1x1 conv, M=576 per block (bf16 MFMA GEMM) ----------------
__global__ __launch_bounds__(512) void k1_qkv(
    const float* __restrict__ x, const u16* __restrict__ Wb,
    const float* __restrict__ Bp, u16* __restrict__ qkv1) {
  int blk = blockIdx.x;               // 2048 = 4 bb * 512 strips
  int bb = blk >> 9, nb = blk & 511;
  int s0 = nb << 7;                   // 128-pixel strip
  int t = threadIdx.x;
  int lane = t & 63, wid = t >> 6;    // 8 waves
  int lg = lane >> 4, lr = lane & 15;
  int wr = wid >> 1, wc = wid & 1;    // wr: group-in-pass, wc: px half

  __shared__ __align__(16) u16 Bt[128*192];   // x^T tile [px][k], XOR-swizzled

  const float* xb = x + (size_t)bb*(192*65536) + s0;
  {
    int px4 = t & 31, kO = t >> 5;
    #pragma unroll
    for (int rnd = 0; rnd < 2; ++rnd, kO += 16) {
      if (kO < 24) {
        float4 f[8];
        #pragma unroll
        for (int j = 0; j < 8; ++j)
          f[j] = *(const float4*)(xb + (size_t)(kO*8 + j)*65536 + px4*4);
        #pragma unroll
        for (int e = 0; e < 4; ++e) {
          int px = px4*4 + e;
          bf16x8 hh;
          #pragma unroll
          for (int j = 0; j < 8; ++j)
            hh[j] = (short)f2bf(((const float*)&f[j])[e]);
          int byte = (px*384 + kO*16) ^ ((px & 7) << 4);
          *(bf16x8*)((char*)Bt + byte) = hh;
        }
      }
    }
  }
  __syncthreads();

  #pragma unroll 1
  for (int pass = 0; pass < 3; ++pass) {
    int g = pass*4 + wr;
    bf16x8 af[3][6];
    #pragma unroll
    for (int mt = 0; mt < 3; ++mt) {
      const u16* wrp = Wb + (size_t)(g*48 + mt*16 + lr)*192 + lg*8;
      #pragma unroll
      for (int ks = 0; ks < 6; ++ks)
        af[mt][ks] = *(const bf16x8*)(wrp + ks*32);
    }
    f32x4 acc[3][4];
    #pragma unroll
    for (int mt = 0; mt < 3; ++mt)
      #pragma unroll
      for (int nt = 0; nt < 4; ++nt)
        acc[mt][nt] = (f32x4){0.f, 0.f, 0.f, 0.f};

    #pragma unroll
    for (int ks = 0; ks < 6; ++ks) {
      bf16x8 bf[4];
      #pragma unroll
      for (int nt = 0; nt < 4; ++nt) {
        int px = wc*64 + nt*16 + lr;
        int byte = (px*384 + ks*64 + lg*16) ^ ((px & 7) << 4);
        bf[nt] = *(const bf16x8*)((const char*)Bt + byte);
      }
      #pragma unroll
      for (int mt = 0; mt < 3; ++mt)
        #pragma unroll
        for (int nt = 0; nt < 4; ++nt)
          acc[mt][nt] = MFMA16(af[mt][ks], bf[nt], acc[mt][nt]);
    }

    u16* dst = qkv1 + ((size_t)(bb*12 + g)*65536 + s0)*48;
    #pragma unroll
    for (int mt = 0; mt < 3; ++mt) {
      float4 bv = *(const float4*)(Bp + g*48 + mt*16 + lg*4);
      #pragma unroll
      for (int nt = 0; nt < 4; ++nt) {
        int px = wc*64 + nt*16 + lr;
        ushort4 o;
        o.x = f2bf(acc[mt][nt][0] + bv.x);
        o.y = f2bf(acc[mt][nt][1] + bv.y);
        o.z = f2bf(acc[mt][nt][2] + bv.z);
        o.w = f2bf(acc[mt][nt][3] + bv.w);
        *(ushort4*)(dst + (size_t)px*48 + mt*16 + lg*4) = o;
      }
    }
  }
}

// ---------------- K2: depthwise 3x3 + Gram partials (q,k) + v store -----------------
// in_t: c-major half-halo, addr = lc*456 + (lc>>3)*8 + hr*24 + hc  (bank-spread bump)
// out_t: pixel-major with 24-u16 row skew: OT(pp,c) = pp*48 + (pp>>4)*24 + c
__global__ __launch_bounds__(256) void k2_dw(
    const u16* __restrict__ qkv1, const float* __restrict__ dw_w,
    const float* __restrict__ dw_b, u16* __restrict__ vd,
    float* __restrict__ partials) {
  int tx = blockIdx.x, ty = blockIdx.y, bb = blockIdx.z;
  int x0 = tx << 4, y0 = ty << 4;
  int t = threadIdx.x;

  __shared__ __align__(16) u16 in_t[10960];   // 24ch half halo, 21920 B
  __shared__ __align__(16) u16 out_t[12648];  // 256px x 48ch + skew, 25296 B
  __shared__ float w9[48*9];
  __shared__ float wb[48];
  float* stage = (float*)in_t;                // f32 reuse (4656 floats <= 10960 u16)

  for (int g = 0; g < 12; ++g) {
    __syncthreads();  // protect in_t(stage)/out_t/w9 reuse from previous iteration
    for (int j = t; j < 480; j += 256) {
      if (j < 432) { int c = j / 9; w9[j] = dw_w[qkv_ch(g, c)*9 + (j % 9)]; }
      else         { int c = j - 432; wb[c] = dw_b[qkv_ch(g, c)]; }
    }
    const u16* src = qkv1 + (size_t)(bb*12 + g) * (65536*48);

    #pragma unroll 1
    for (int h = 0; h < 2; ++h) {
      if (h) __syncthreads();                  // conv(h-1) finished reading in_t
      // stage 24-ch half halo: 324 px * 3 uint4 chunks
      #pragma unroll
      for (int r = 0; r < 4; ++r) {
        int j = t + (r << 8);
        if (j < 972) {
          int hp = j / 3, c16 = j - (j/3)*3;
          int hr = hp / 18, hc = hp - hr*18;
          int hy = y0 - 1 + hr, hx = x0 - 1 + hc;
          uint4 v = {0u, 0u, 0u, 0u};
          if (hy >= 0 && hy < 256 && hx >= 0 && hx < 256)
            v = *(const uint4*)(src + ((size_t)hy*256 + hx)*48 + h*24 + c16*8);
          const u16* us = (const u16*)&v;
          int base = c16*(8*456 + 8) + hr*24 + hc;
          #pragma unroll
          for (int cc = 0; cc < 8; ++cc)
            in_t[base + cc*456] = us[cc];
        }
      }
      __syncthreads();

      // dw conv: item = (lc, 16-px row); wide LDS reads, taps in regs
      #pragma unroll 1
      for (int s2 = 0; s2 < 2; ++s2) {
        int item = t + (s2 << 8);
        if (item < 384) {
          int lc = item % 24, row = item / 24;
          int c = h*24 + lc;
          float wv[9];
          #pragma unroll
          for (int i = 0; i < 9; ++i) wv[i] = w9[c*9 + i];
          float bias = wb[c];
          int ibase = lc*456 + (lc >> 3)*8;
          float rowf[3][18];
          #pragma unroll
          for (int dy = 0; dy < 3; ++dy) {
            int base = ibase + (row + dy)*24;
            u16 hrow[18];
            *(uint4*)(hrow)     = *(const uint4*)(in_t + base);
            *(uint4*)(hrow + 8) = *(const uint4*)(in_t + base + 8);
            *(uint*)(hrow + 16) = *(const uint*)(in_t + base + 16);
            #pragma unroll
            for (int i2 = 0; i2 < 18; ++i2) rowf[dy][i2] = bf2f(hrow[i2]);
          }
          int obase = row*792 + c;             // row*(16*48+24) + c
          #pragma unroll
          for (int p = 0; p < 16; ++p) {
            float acc = bias;
            #pragma unroll
            for (int dy = 0; dy < 3; ++dy)
              acc += rowf[dy][p]*wv[dy*3] + rowf[dy][p+1]*wv[dy*3+1] + rowf[dy][p+2]*wv[dy*3+2];
            out_t[obase + p*48] = f2bf(acc);
          }
        }
      }
    }
    __syncthreads();

    if (g < 8) {
      // Gram: 36 pairs (4x4 c,d tiles) x 8 px-chunks + 12 diag groups x 8 chunks
      #pragma unroll 1
      for (int s2 = 0; s2 < 2; ++s2) {
        int jj = t + (s2 << 8);
        if (jj < 384) {
          if (jj < 288) {
            int pair = jj % 36, chunk = jj / 36;
            int c0 = (pair / 6)*4, d0 = 24 + (pair % 6)*4;
            float a16[16];
            #pragma unroll
            for (int e = 0; e < 16; ++e) a16[e] = 0.f;
            int pb = chunk*(32*48) + chunk*(2*24);   // OT(chunk*32, 0)
            for (int pi = 0; pi < 32; ++pi) {
              int off = pb + pi*48 + ((pi >> 4)*24);
              ushort4 qv = *(const ushort4*)(out_t + off + c0);
              ushort4 kv = *(const ushort4*)(out_t + off + d0);
              float qf[4] = {bf2f(qv.x), bf2f(qv.y), bf2f(qv.z), bf2f(qv.w)};
              float kf[4] = {bf2f(kv.x), bf2f(kv.y), bf2f(kv.z), bf2f(kv.w)};
              #pragma unroll
              for (int ii = 0; ii < 4; ++ii)
                #pragma unroll
                for (int dj = 0; dj < 4; ++dj)
                  a16[ii*4 + dj] += qf[ii] * kf[dj];
            }
            #pragma unroll
            for (int e = 0; e < 16; ++e) stage[(pair*8 + chunk)*16 + e] = a16[e];
          } else {
            int dj2 = jj - 288;
            int grp = dj2 % 12, chunk = dj2 / 12;
            int c0 = grp*4;
            float a4[4] = {0.f, 0.f, 0.f, 0.f};
            int pb = chunk*(32*48) + chunk*(2*24);
            for (int pi = 0; pi < 32; ++pi) {
              int off = pb + pi*48 + ((pi >> 4)*24);
              ushort4 qv = *(const ushort4*)(out_t + off + c0);
              float q0 = bf2f(qv.x), q1 = bf2f(qv.y), q2 = bf2f(qv.z), q3 = bf2f(qv.w);
              a4[0] += q0*q0; a4[1] += q1*q1; a4[2] += q2*q2; a4[3] += q3*q3;
            }
            #pragma unroll
            for (int e = 0; e < 4; ++e) stage[4608 + (grp*8 + chunk)*4 + e] = a4[e];
          }
        }
      }
      __syncthreads();
      float* pdst = partials + (((size_t)bb*256 + (ty*16 + tx))*8 + g) * 640;
      for (int e = t; e < 624; e += 256) {
        float s = 0.f;
        if (e < 576) {
          int c = e / 24, d = e % 24;
          int pair = (c >> 2)*6 + (d >> 2);
          int idx = (c & 3)*4 + (d & 3);
          #pragma unroll
          for (int ch = 0; ch < 8; ++ch) s += stage[(pair*8 + ch)*16 + idx];
        } else {
          int cc = e - 576;
          int grp = cc >> 2, ii = cc & 3;
          #pragma unroll
          for (int ch = 0; ch < 8; ++ch) s += stage[4608 + (grp*8 + ch)*4 + ii];
        }
        pdst[e] = s;
      }
    } else {
      // v groups: write vd[b][s][192] bf16
      u16* dst = vd + (size_t)bb * (65536*192);
      #pragma unroll
      for (int i = 0; i < 6; ++i) {
        int j = t + (i << 8);
        int pp = j / 6, c16 = j % 6;
        int py = pp >> 4, px = pp & 15;
        size_t s = (size_t)(y0 + py)*256 + (x0 + px);
        uint4 v = *(const uint4*)(out_t + pp*48 + py*24 + c16*8);
        *(uint4*)(dst + s*192 + (g - 8)*48 + c16*8) = v;
      }
    }
  }
}

// ---------------- K3a: reduce Gram partials (8 chunks of 32 blocks) -----------------
__global__ __launch_bounds__(256) void k3a(
    const float* __restrict__ partials, float* __restrict__ G2) {
  int bb = blockIdx.x, h = blockIdx.y, ch = blockIdx.z;  // 4,8,8
  int t = threadIdx.x;
  for (int e = t; e < 624; e += 256) {
    const float* p = partials + ((size_t)(bb*256 + ch*32)*8 + h)*640 + e;
    float s = 0.f;
    #pragma unroll 4
    for (int blk = 0; blk < 32; ++blk) s += p[(size_t)blk * (8*640)];
    G2[(size_t)((bb*8 + h)*8 + ch)*640 + e] = s;
  }
}

// ---------------- K3b: norms + softmax + fold proj into M_b[192][192] --------------
__global__ __launch_bounds__(256) void k3b(
    const float* __restrict__ G2, const float* __restrict__ scale,
    const float* __restrict__ proj_w, u16* __restrict__ M) {
  int bb = blockIdx.x;
  int t = threadIdx.x;
  __shared__ float Gs[8*640];
  __shared__ float attn[8*24*24];
  for (int j = t; j < 5120; j += 256) {
    int h = j / 640, e = j % 640;
    float s = 0.f;
    #pragma unroll
    for (int ch = 0; ch < 8; ++ch)
      s += G2[(size_t)((bb*8 + h)*8 + ch)*640 + e];
    Gs[j] = s;
  }
  __syncthreads();
  if (t < 192) {
    int h = t / 24, c = t % 24;
    const float* Gh = Gs + h*640;
    float qn = fmaxf(sqrtf(fmaxf(Gh[576 + c], 0.f)), 1e-12f);
    float sc = scale[h];
    float L[24];
    float mx = -1e30f;
    #pragma unroll
    for (int d = 0; d < 24; ++d) {
      float kn = fmaxf(sqrtf(fmaxf(Gh[600 + d], 0.f)), 1e-12f);
      L[d] = Gh[c*24 + d] / (qn * kn) * sc;
      mx = fmaxf(mx, L[d]);
    }
    float ssum = 0.f;
    #pragma unroll
    for (int d = 0; d < 24; ++d) { L[d] = __expf(L[d] - mx); ssum += L[d]; }
    float inv = 1.f / ssum;
    #pragma unroll
    for (int d = 0; d < 24; ++d) attn[(h*24 + c)*24 + d] = L[d] * inv;
  }
  __syncthreads();
  for (int j = t; j < 36864; j += 256) {
    int co = j / 192, cd = j % 192;
    int h = cd / 24, d = cd % 24;
    const float* Pr = proj_w + co*192 + h*24;
    const float* Ar = attn + h*576 + d;
    float s = 0.f;
    #pragma unroll
    for (int c = 0; c < 24; ++c) s += Pr[c] * Ar[c*24];
    M[(size_t)bb*36864 + j] = f2bf(s);
  }
}

// ---------------- K4: y = M_b @ v + proj_b (bf16 MFMA GEMM, fp32 out) --------------
__global__ __launch_bounds__(256) void k4_out(
    const u16* __restrict__ vd, const u16* __restrict__ M,
    const float* __restrict__ proj_b, float* __restrict__ out) {
  int p = blockIdx.x;
  int xcd = p & 7, w = p >> 3;
  int mb = w & 1;
  int pr = xcd*512 + (w >> 1);
  int bb = pr >> 10, nb = pr & 1023;
  int s0 = nb << 6;
  int t = threadIdx.x;
  int lane = t & 63, wid = t >> 6;
  int lg = lane >> 4, lr = lane & 15;

  __shared__ __align__(16) u16 A[96*192];
  __shared__ __align__(16) u16 B[64*192];

  const u16* Ms = M + ((size_t)bb*192 + mb*96) * 192;
  for (int j = t; j < 2304; j += 256) {
    int m = j / 24, c16 = j % 24;
    uint4 v = *(const uint4*)(Ms + m*192 + c16*8);
    int byte = (m*384 + c16*16) ^ ((m & 7) << 4);
    *(uint4*)((char*)A + byte) = v;
  }
  const u16* Bs = vd + ((size_t)bb*65536 + s0) * 192;
  for (int j = t; j < 1536; j += 256) {
    int px = j / 24, c16 = j % 24;
    uint4 v = *(const uint4*)(Bs + px*192 + c16*8);
    int byte = (px*384 + c16*16) ^ ((px & 7) << 4);
    *(uint4*)((char*)B + byte) = v;
  }
  __syncthreads();

  int wr = wid >> 1, wc = wid & 1;
  f32x4 acc[3][2];
  #pragma unroll
  for (int mt = 0; mt < 3; ++mt)
    #pragma unroll
    for (int nt = 0; nt < 2; ++nt)
      acc[mt][nt] = (f32x4){0.f, 0.f, 0.f, 0.f};

  #pragma unroll
  for (int ks = 0; ks < 6; ++ks) {
    bf16x8 af[3], bf[2];
    #pragma unroll
    for (int mt = 0; mt < 3; ++mt) {
      int m = wr*48 + mt*16 + lr;
      int byte = (m*384 + ks*64 + lg*16) ^ ((m & 7) << 4);
      af[mt] = *(const bf16x8*)((const char*)A + byte);
    }
    #pragma unroll
    for (int nt = 0; nt < 2; ++nt) {
      int px = wc*32 + nt*16 + lr;
      int byte = (px*384 + ks*64 + lg*16) ^ ((px & 7) << 4);
      bf[nt] = *(const bf16x8*)((const char*)B + byte);
    }
    #pragma unroll
    for (int mt = 0; mt < 3; ++mt)
      #pragma unroll
      for (int nt = 0; nt < 2; ++nt)
        acc[mt][nt] = MFMA16(af[mt], bf[nt], acc[mt][nt]);
  }
  __syncthreads();
  float* stg = (float*)A;
  #pragma unroll
  for (int mt = 0; mt < 3; ++mt)
    #pragma unroll
    for (int nt = 0; nt < 2; ++nt) {
      int m0 = wr*48 + mt*16 + lg*4;
      int px = wc*32 + nt*16 + lr;
      #pragma unroll
      for (int r = 0; r < 4; ++r)
        stg[(m0 + r)*68 + px] = acc[mt][nt][r];
    }
  __syncthreads();
  float* dst = out + ((size_t)bb*192 + mb*96) * 65536 + s0;
  const float* pb = proj_b + mb*96;
  #pragma unroll
  for (int i = 0; i < 6; ++i) {
    int j = t + (i << 8);
    int m = j >> 4, c4 = j & 15;
    float4 v = *(const float4*)(stg + m*68 + c4*4);
    float b = pb[m];
    v.x += b; v.y += b; v.z += b; v.w += b;
    *(float4*)(dst + (size_t)m*65536 + c4*4) = v;
  }
}

extern "C" void kernel_launch(void* const* d_in, const int* in_sizes, int n_in,
                              void* d_out, int out_size, void* d_ws, size_t ws_size,
                              hipStream_t stream) {
  (void)in_sizes; (void)n_in; (void)out_size; (void)ws_size;
  const float* x      = (const float*)d_in[0];
  const float* qkv_w  = (const float*)d_in[1];
  const float* qkv_b  = (const float*)d_in[2];
  const float* dw_w   = (const float*)d_in[3];
  const float* dw_b   = (const float*)d_in[4];
  const float* scale  = (const float*)d_in[5];
  const float* proj_w = (const float*)d_in[6];
  const float* proj_b = (const float*)d_in[7];
  float* out = (float*)d_out;
  char* ws = (char*)d_ws;

  u16*   qkv1     = (u16*)(ws);
  u16*   vd       = (u16*)(ws + 301989888ULL);
  float* partials = (float*)(ws + 402653184ULL);
  u16*   Wb       = (u16*)(ws + 402653184ULL);
  float* Bp       = (float*)(ws + 402653184ULL + 221184ULL);
  float* G2       = (float*)(ws);
  u16*   M        = (u16*)(ws + 1048576ULL);

  k0_wb<<<dim3(432), dim3(256), 0, stream>>>(qkv_w, qkv_b, Wb, Bp);
  k1_qkv<<<dim3(2048), dim3(512), 0, stream>>>(x, Wb, Bp, qkv1);
  k2_dw<<<dim3(16, 16, 4), dim3(256), 0, stream>>>(qkv1, dw_w, dw_b, vd, partials);
  k3a<<<dim3(4, 8, 8), dim3(256), 0, stream>>>(partials, G2);
  k3b<<<dim3(4), dim3(256), 0, stream>>>(G2, scale, proj_w, M);
  k4_out<<<dim3(8192), dim3(256), 0, stream>>>(vd, M, proj_b, out);
}

// Round 5
// 641.680 us; speedup vs baseline: 2.3427x; 1.1929x over previous
//
#include <hip/hip_runtime.h>
#include <hip/hip_bf16.h>

typedef unsigned short u16;
typedef __attribute__((ext_vector_type(8))) short bf16x8;
typedef __attribute__((ext_vector_type(4))) float f32x4;

#define MFMA16(a,b,c) __builtin_amdgcn_mfma_f32_16x16x32_bf16(a,b,c,0,0,0)

__device__ __forceinline__ u16 f2bf(float f) {
  union { float f; unsigned u; } v; v.f = f;
  return (u16)((v.u + 0x7fffu + ((v.u >> 16) & 1u)) >> 16);
}
__device__ __forceinline__ float bf2f(u16 h) {
  union { unsigned u; float f; } v; v.u = ((unsigned)h) << 16;
  return v.f;
}
// group g in 0..11 (8 qk-head groups of 24q+24k, then 4 v-groups of 48), c in 0..47
__device__ __forceinline__ int qkv_ch(int g, int c) {
  if (g < 8) return (c < 24) ? (g*24 + c) : (192 + g*24 + (c - 24));
  return 384 + (g - 8)*48 + c;
}

// ---------------- K0: pre-permute + bf16-convert qkv weights ------------------------
__global__ __launch_bounds__(256) void k0_wb(
    const float* __restrict__ qkv_w, const float* __restrict__ qkv_b,
    u16* __restrict__ Wb, float* __restrict__ Bp) {
  int j = blockIdx.x*256 + threadIdx.x;          // 432 blocks -> 110592 = 576*192
  int m = j / 192, k = j % 192;
  Wb[j] = f2bf(qkv_w[qkv_ch(m/48, m%48)*192 + k]);
  if (j < 576) Bp[j] = qkv_b[qkv_ch(j/48, j%48)];
}

// ---------------- K1: qkv 1x1 conv, M=576 per block (bf16 MFMA GEMM) ----------------
__global__ __launch_bounds__(512) void k1_qkv(
    const float* __restrict__ x, const u16* __restrict__ Wb,
    const float* __restrict__ Bp, u16* __restrict__ qkv1) {
  int blk = blockIdx.x;               // 2048 = 4 bb * 512 strips
  int bb = blk >> 9, nb = blk & 511;
  int s0 = nb << 7;                   // 128-pixel strip
  int t = threadIdx.x;
  int lane = t & 63, wid = t >> 6;    // 8 waves
  int lg = lane >> 4, lr = lane & 15;
  int wr = wid >> 1, wc = wid & 1;

  __shared__ __align__(16) u16 Bt[128*192];   // x^T tile [px][k], XOR-swizzled

  // stage x strip: thread -> (px4 = t>>4, kO = t&15 / +16); write sb = kO^(px&7): conflict-free
  const float* xb = x + (size_t)bb*(192*65536) + s0;
  {
    int px4 = t >> 4;                 // 0..31
    int kO = t & 15;
    #pragma unroll
    for (int rnd = 0; rnd < 2; ++rnd, kO += 16) {
      if (kO < 24) {
        float4 f[8];
        #pragma unroll
        for (int j = 0; j < 8; ++j)
          f[j] = *(const float4*)(xb + (size_t)(kO*8 + j)*65536 + px4*4);
        #pragma unroll
        for (int e = 0; e < 4; ++e) {
          int px = px4*4 + e;
          bf16x8 hh;
          #pragma unroll
          for (int j = 0; j < 8; ++j)
            hh[j] = (short)f2bf(((const float*)&f[j])[e]);
          int byte = (px*384 + kO*16) ^ ((px & 7) << 4);
          *(bf16x8*)((char*)Bt + byte) = hh;
        }
      }
    }
  }
  __syncthreads();

  #pragma unroll 1
  for (int pass = 0; pass < 3; ++pass) {
    int g = pass*4 + wr;
    bf16x8 af[3][6];
    #pragma unroll
    for (int mt = 0; mt < 3; ++mt) {
      const u16* wrp = Wb + (size_t)(g*48 + mt*16 + lr)*192 + lg*8;
      #pragma unroll
      for (int ks = 0; ks < 6; ++ks)
        af[mt][ks] = *(const bf16x8*)(wrp + ks*32);
    }
    f32x4 acc[3][4];
    #pragma unroll
    for (int mt = 0; mt < 3; ++mt)
      #pragma unroll
      for (int nt = 0; nt < 4; ++nt)
        acc[mt][nt] = (f32x4){0.f, 0.f, 0.f, 0.f};

    #pragma unroll
    for (int ks = 0; ks < 6; ++ks) {
      bf16x8 bf[4];
      #pragma unroll
      for (int nt = 0; nt < 4; ++nt) {
        int px = wc*64 + nt*16 + lr;
        int byte = (px*384 + ks*64 + lg*16) ^ ((px & 7) << 4);
        bf[nt] = *(const bf16x8*)((const char*)Bt + byte);
      }
      #pragma unroll
      for (int mt = 0; mt < 3; ++mt)
        #pragma unroll
        for (int nt = 0; nt < 4; ++nt)
          acc[mt][nt] = MFMA16(af[mt][ks], bf[nt], acc[mt][nt]);
    }

    u16* dst = qkv1 + ((size_t)(bb*12 + g)*65536 + s0)*48;
    #pragma unroll
    for (int mt = 0; mt < 3; ++mt) {
      float4 bv = *(const float4*)(Bp + g*48 + mt*16 + lg*4);
      #pragma unroll
      for (int nt = 0; nt < 4; ++nt) {
        int px = wc*64 + nt*16 + lr;
        ushort4 o;
        o.x = f2bf(acc[mt][nt][0] + bv.x);
        o.y = f2bf(acc[mt][nt][1] + bv.y);
        o.z = f2bf(acc[mt][nt][2] + bv.z);
        o.w = f2bf(acc[mt][nt][3] + bv.w);
        *(ushort4*)(dst + (size_t)px*48 + mt*16 + lg*4) = o;
      }
    }
  }
}

// ---------------- K2: depthwise 3x3 + MFMA Gram (q,k) + v store ---------------------
// buf0: in_t 16-ch third halo, addr = lc*456 + 8*(lc>>3) + hr*24 + hc  (union: gram stage f32)
// buf1 (g<8): out_tT[c 0..55][px 0..255], stride 264 u16 (rows 48-55 zeroed)
// buf1 (g>=8): out_t px-major + 24-u16 row skew: addr = row*792 + p*48 + c
__global__ __launch_bounds__(256) void k2_dw(
    const u16* __restrict__ qkv1, const float* __restrict__ dw_w,
    const float* __restrict__ dw_b, u16* __restrict__ vd,
    float* __restrict__ partials) {
  int tx = blockIdx.x, ty = blockIdx.y, bb = blockIdx.z;
  int x0 = tx << 4, y0 = ty << 4;
  int t = threadIdx.x;

  __shared__ __align__(16) u16 buf0[9472];    // 18944 B
  __shared__ __align__(16) u16 buf1[14784];   // 29568 B
  __shared__ float w9[432];
  __shared__ float wb[48];
  float* stg = (float*)buf0;

  // zero out_tT pad rows 48..55 (never written again; v path stays < 12672)
  for (int j = t; j < 2112; j += 256) buf1[12672 + j] = 0;

  for (int g = 0; g < 12; ++g) {
    __syncthreads();                           // prev group fully done with buf0/buf1/w9
    for (int j = t; j < 480; j += 256) {
      if (j < 432) { int c = j / 9; w9[j] = dw_w[qkv_ch(g, c)*9 + (j % 9)]; }
      else         { int c = j - 432; wb[c] = dw_b[qkv_ch(g, c)]; }
    }
    const u16* src = qkv1 + (size_t)(bb*12 + g) * (65536*48);

    #pragma unroll 1
    for (int h = 0; h < 3; ++h) {              // 16-channel thirds
      // stage: 324 halo px * 2 uint4 chunks
      #pragma unroll
      for (int r = 0; r < 3; ++r) {
        int j = t + (r << 8);
        if (j < 648) {
          int hp = j >> 1, c16 = j & 1;
          int hr = hp / 18, hc = hp - hr*18;
          int hy = y0 - 1 + hr, hx = x0 - 1 + hc;
          uint4 v = {0u, 0u, 0u, 0u};
          if (hy >= 0 && hy < 256 && hx >= 0 && hx < 256)
            v = *(const uint4*)(src + ((size_t)hy*256 + hx)*48 + h*16 + c16*8);
          const u16* us = (const u16*)&v;
          int base = c16*(8*456 + 8) + hr*24 + hc;
          #pragma unroll
          for (int cc = 0; cc < 8; ++cc)
            buf0[base + cc*456] = us[cc];
        }
      }
      __syncthreads();

      // conv: 256 items = 16 ch x 16 rows
      {
        int lc = t & 15, row = t >> 4;
        int c = h*16 + lc;
        float wv[9];
        #pragma unroll
        for (int i = 0; i < 9; ++i) wv[i] = w9[c*9 + i];
        float bias = wb[c];
        int ibase = lc*456 + ((lc >> 3) << 3);
        float rowf[3][18];
        #pragma unroll
        for (int dy = 0; dy < 3; ++dy) {
          int base = ibase + (row + dy)*24;
          u16 hrow[18];
          *(uint4*)(hrow)      = *(const uint4*)(buf0 + base);
          *(uint4*)(hrow + 8)  = *(const uint4*)(buf0 + base + 8);
          *(uint*)(hrow + 16)  = *(const uint*)(buf0 + base + 16);
          #pragma unroll
          for (int i2 = 0; i2 < 18; ++i2) rowf[dy][i2] = bf2f(hrow[i2]);
        }
        float o[16];
        #pragma unroll
        for (int p = 0; p < 16; ++p) {
          float a = bias;
          #pragma unroll
          for (int dy = 0; dy < 3; ++dy)
            a += rowf[dy][p]*wv[dy*3] + rowf[dy][p+1]*wv[dy*3+1] + rowf[dy][p+2]*wv[dy*3+2];
          o[p] = a;
        }
        if (g < 8) {
          unsigned ow[8];
          #pragma unroll
          for (int i = 0; i < 8; ++i)
            asm volatile("v_cvt_pk_bf16_f32 %0, %1, %2"
                         : "=v"(ow[i]) : "v"(o[2*i]), "v"(o[2*i + 1]));
          u16* dsth = buf1 + c*264 + row*16;
          *(uint4*)(dsth)     = make_uint4(ow[0], ow[1], ow[2], ow[3]);
          *(uint4*)(dsth + 8) = make_uint4(ow[4], ow[5], ow[6], ow[7]);
        } else {
          int obase = row*792 + c;
          #pragma unroll
          for (int p = 0; p < 16; ++p)
            buf1[obase + p*48] = f2bf(o[p]);
        }
      }
      __syncthreads();
    }

    if (g < 8) {
      // Gram via MFMA: A=q rows 0-23, B=k rows 24-47 of out_tT; diag via mfma(x,x)
      int lane = t & 63, w = t >> 6;
      int lr = lane & 15, lg = lane >> 4;
      f32x4 cc4[8];
      #pragma unroll
      for (int i = 0; i < 8; ++i) cc4[i] = (f32x4){0.f, 0.f, 0.f, 0.f};
      #pragma unroll
      for (int ks = 0; ks < 2; ++ks) {
        int pxb = w*64 + ks*32 + lg*8;
        bf16x8 aq[2], ak[2];
        aq[0] = *(const bf16x8*)(buf1 + (size_t)lr*264 + pxb);
        aq[1] = *(const bf16x8*)(buf1 + (size_t)(16 + lr)*264 + pxb);
        ak[0] = *(const bf16x8*)(buf1 + (size_t)(24 + lr)*264 + pxb);
        ak[1] = *(const bf16x8*)(buf1 + (size_t)(40 + lr)*264 + pxb);
        cc4[0] = MFMA16(aq[0], ak[0], cc4[0]);
        cc4[1] = MFMA16(aq[0], ak[1], cc4[1]);
        cc4[2] = MFMA16(aq[1], ak[0], cc4[2]);
        cc4[3] = MFMA16(aq[1], ak[1], cc4[3]);
        cc4[4] = MFMA16(aq[0], aq[0], cc4[4]);   // qq: diag c 0-15
        cc4[5] = MFMA16(aq[1], aq[1], cc4[5]);   // qq: diag c 16-23
        cc4[6] = MFMA16(ak[0], ak[0], cc4[6]);   // kk: diag d 0-15
        cc4[7] = MFMA16(ak[1], ak[1], cc4[7]);   // kk: diag d 16-23
      }
      // stage cross tiles [w][tile][row*17+col] + diag [w][qk][ch]
      #pragma unroll
      for (int tile = 0; tile < 4; ++tile) {
        float* sp = stg + w*1088 + tile*272 + lr;
        #pragma unroll
        for (int r = 0; r < 4; ++r)
          sp[(lg*4 + r)*17] = cc4[tile][r];
      }
      {
        int r = lr - lg*4;
        if (r >= 0 && r < 4) {
          stg[4352 + w*96 + lr]      = cc4[4][r];
          stg[4352 + w*96 + 48 + lr] = cc4[6][r];
          if (lr < 8) {
            stg[4352 + w*96 + 16 + lr]      = cc4[5][r];
            stg[4352 + w*96 + 48 + 16 + lr] = cc4[7][r];
          }
        }
      }
      __syncthreads();
      float* pdst = partials + (((size_t)bb*256 + (ty*16 + tx))*8 + g) * 640;
      for (int e = t; e < 624; e += 256) {
        float s = 0.f;
        if (e < 576) {
          int c = e / 24, d = e % 24;
          int off = ((c >> 4)*2 + (d >> 4))*272 + (c & 15)*17 + (d & 15);
          #pragma unroll
          for (int w2 = 0; w2 < 4; ++w2) s += stg[w2*1088 + off];
        } else {
          int cc2 = e - 576;                  // 0-23 q, 24-47 k
          int qk = cc2 / 24, ch = cc2 % 24;
          #pragma unroll
          for (int w2 = 0; w2 < 4; ++w2) s += stg[4352 + w2*96 + qk*48 + ch];
        }
        pdst[e] = s;
      }
    } else {
      u16* dst = vd + (size_t)bb * (65536*192);
      #pragma unroll
      for (int i = 0; i < 6; ++i) {
        int j = t + (i << 8);
        int pp = j / 6, c16 = j % 6;
        int py = pp >> 4, px = pp & 15;
        size_t s = (size_t)(y0 + py)*256 + (x0 + px);
        uint4 v = *(const uint4*)(buf1 + pp*48 + py*24 + c16*8);
        *(uint4*)(dst + s*192 + (g - 8)*48 + c16*8) = v;
      }
    }
  }
}

// ---------------- K3a: reduce Gram partials (8 chunks of 32 blocks) -----------------
__global__ __launch_bounds__(256) void k3a(
    const float* __restrict__ partials, float* __restrict__ G2) {
  int bb = blockIdx.x, h = blockIdx.y, ch = blockIdx.z;  // 4,8,8
  int t = threadIdx.x;
  for (int e = t; e < 624; e += 256) {
    const float* p = partials + ((size_t)(bb*256 + ch*32)*8 + h)*640 + e;
    float s = 0.f;
    #pragma unroll 4
    for (int blk = 0; blk < 32; ++blk) s += p[(size_t)blk * (8*640)];
    G2[(size_t)((bb*8 + h)*8 + ch)*640 + e] = s;
  }
}

// ---------------- K3b: norms + softmax + fold proj into M_b[192][192] --------------
__global__ __launch_bounds__(256) void k3b(
    const float* __restrict__ G2, const float* __restrict__ scale,
    const float* __restrict__ proj_w, u16* __restrict__ M) {
  int bb = blockIdx.x;
  int t = threadIdx.x;
  __shared__ float Gs[8*640];
  __shared__ float attn[8*24*24];
  for (int j = t; j < 5120; j += 256) {
    int h = j / 640, e = j % 640;
    float s = 0.f;
    #pragma unroll
    for (int ch = 0; ch < 8; ++ch)
      s += G2[(size_t)((bb*8 + h)*8 + ch)*640 + e];
    Gs[j] = s;
  }
  __syncthreads();
  if (t < 192) {
    int h = t / 24, c = t % 24;
    const float* Gh = Gs + h*640;
    float qn = fmaxf(sqrtf(fmaxf(Gh[576 + c], 0.f)), 1e-12f);
    float sc = scale[h];
    float L[24];
    float mx = -1e30f;
    #pragma unroll
    for (int d = 0; d < 24; ++d) {
      float kn = fmaxf(sqrtf(fmaxf(Gh[600 + d], 0.f)), 1e-12f);
      L[d] = Gh[c*24 + d] / (qn * kn) * sc;
      mx = fmaxf(mx, L[d]);
    }
    float ssum = 0.f;
    #pragma unroll
    for (int d = 0; d < 24; ++d) { L[d] = __expf(L[d] - mx); ssum += L[d]; }
    float inv = 1.f / ssum;
    #pragma unroll
    for (int d = 0; d < 24; ++d) attn[(h*24 + c)*24 + d] = L[d] * inv;
  }
  __syncthreads();
  for (int j = t; j < 36864; j += 256) {
    int co = j / 192, cd = j % 192;
    int h = cd / 24, d = cd % 24;
    const float* Pr = proj_w + co*192 + h*24;
    const float* Ar = attn + h*576 + d;
    float s = 0.f;
    #pragma unroll
    for (int c = 0; c < 24; ++c) s += Pr[c] * Ar[c*24];
    M[(size_t)bb*36864 + j] = f2bf(s);
  }
}

// ---------------- K4: y = M_b @ v + proj_b — zero-LDS, zero-barrier GEMM -----------
__global__ __launch_bounds__(256) void k4_out(
    const u16* __restrict__ vd, const u16* __restrict__ M,
    const float* __restrict__ proj_b, float* __restrict__ out) {
  int p = blockIdx.x;                 // 4096, XCD-swizzled
  int xcd = p & 7, q = p >> 3;
  int pr = xcd*512 + q;               // 0..4095
  int bb = pr >> 10, nb = pr & 1023;
  int s0 = nb << 6;                   // 64 pixels
  int t = threadIdx.x;
  int lane = t & 63, wid = t >> 6;    // wave = 48 M-rows x 64 px
  int lg = lane >> 4, lr = lane & 15;

  const u16* Mb = M + (size_t)bb*36864;
  const u16* Bs = vd + ((size_t)bb*65536 + s0)*192;

  f32x4 acc[3][4];
  #pragma unroll
  for (int mt = 0; mt < 3; ++mt)
    #pragma unroll
    for (int nt = 0; nt < 4; ++nt)
      acc[mt][nt] = (f32x4){0.f, 0.f, 0.f, 0.f};

  #pragma unroll
  for (int ks = 0; ks < 6; ++ks) {
    bf16x8 bf[4], af[3];
    #pragma unroll
    for (int nt = 0; nt < 4; ++nt)
      bf[nt] = *(const bf16x8*)(Bs + (size_t)(nt*16 + lr)*192 + ks*32 + lg*8);
    #pragma unroll
    for (int mt = 0; mt < 3; ++mt)
      af[mt] = *(const bf16x8*)(Mb + (size_t)(wid*48 + mt*16 + lr)*192 + ks*32 + lg*8);
    #pragma unroll
    for (int mt = 0; mt < 3; ++mt)
      #pragma unroll
      for (int nt = 0; nt < 4; ++nt)
        acc[mt][nt] = MFMA16(af[mt], bf[nt], acc[mt][nt]);
  }

  float* dst = out + (size_t)bb*(192*65536) + s0;
  #pragma unroll
  for (int mt = 0; mt < 3; ++mt) {
    int m0 = wid*48 + mt*16 + lg*4;
    #pragma unroll
    for (int r = 0; r < 4; ++r) {
      float bias = proj_b[m0 + r];
      #pragma unroll
      for (int nt = 0; nt < 4; ++nt)
        dst[(size_t)(m0 + r)*65536 + nt*16 + lr] = acc[mt][nt][r] + bias;
    }
  }
}

extern "C" void kernel_launch(void* const* d_in, const int* in_sizes, int n_in,
                              void* d_out, int out_size, void* d_ws, size_t ws_size,
                              hipStream_t stream) {
  (void)in_sizes; (void)n_in; (void)out_size; (void)ws_size;
  const float* x      = (const float*)d_in[0];
  const float* qkv_w  = (const float*)d_in[1];
  const float* qkv_b  = (const float*)d_in[2];
  const float* dw_w   = (const float*)d_in[3];
  const float* dw_b   = (const float*)d_in[4];
  const float* scale  = (const float*)d_in[5];
  const float* proj_w = (const float*)d_in[6];
  const float* proj_b = (const float*)d_in[7];
  float* out = (float*)d_out;
  char* ws = (char*)d_ws;

  u16*   qkv1     = (u16*)(ws);
  u16*   vd       = (u16*)(ws + 301989888ULL);
  float* partials = (float*)(ws + 402653184ULL);
  u16*   Wb       = (u16*)(ws + 402653184ULL);
  float* Bp       = (float*)(ws + 402653184ULL + 221184ULL);
  float* G2       = (float*)(ws);
  u16*   M        = (u16*)(ws + 1048576ULL);

  k0_wb<<<dim3(432), dim3(256), 0, stream>>>(qkv_w, qkv_b, Wb, Bp);
  k1_qkv<<<dim3(2048), dim3(512), 0, stream>>>(x, Wb, Bp, qkv1);
  k2_dw<<<dim3(16, 16, 4), dim3(256), 0, stream>>>(qkv1, dw_w, dw_b, vd, partials);
  k3a<<<dim3(4, 8, 8), dim3(256), 0, stream>>>(partials, G2);
  k3b<<<dim3(4), dim3(256), 0, stream>>>(G2, scale, proj_w, M);
  k4_out<<<dim3(4096), dim3(256), 0, stream>>>(vd, M, proj_b, out);
}